// Round 12
// baseline (50.170 us; speedup 1.0000x reference)
//
#include <hip/hip_runtime.h>

// PointPillarsScatter, round 12: v5 gather + phase-grouped memory ops.
// Per thread (one cell-quad, C=64): 4 phases of 16 channels; each phase
// issues 16 masked float4 loads back-to-back, then 16 transposed float4
// stores back-to-back -> 4x coarser R/W alternation (HBM turnaround
// reduction). Plain stores (nt regressed in r9); scalar geometry.

__global__ void pps_build_idx(const int* __restrict__ coords,
                              const int* __restrict__ nz_p,
                              const int* __restrict__ ny_p,
                              const int* __restrict__ nx_p,
                              int* __restrict__ idxmap, int n_points) {
    int n = blockIdx.x * blockDim.x + threadIdx.x;
    if (n >= n_points) return;
    int nz = nz_p[0], ny = ny_p[0], nx = nx_p[0];
    long long spatial = (long long)nz * ny * nx;
    int b = coords[4 * n + 0];
    int z = coords[4 * n + 1];
    int y = coords[4 * n + 2];
    int x = coords[4 * n + 3];
    // faithful to reference: per-sample index = z*nz + y*nx + x
    long long cell = b * spatial + (long long)z * nz + (long long)y * nx + x;
    idxmap[cell] = n;
}

// C == 64 specialized, phase-grouped loads/stores
__global__ __launch_bounds__(256)
void pps_gather_v7(const float* __restrict__ vf,
                   const int* __restrict__ idxmap,
                   const int* __restrict__ nz_p,
                   const int* __restrict__ ny_p,
                   const int* __restrict__ nx_p,
                   float* __restrict__ out,
                   long long ncells) {
    const int spatial =
        __builtin_amdgcn_readfirstlane(nz_p[0] * ny_p[0] * nx_p[0]);
    const long long nquads = (ncells + 3) >> 2;
    long long q = blockIdx.x * 256LL + threadIdx.x;
    if (q >= nquads) return;

    long long cell = q << 2;
    unsigned int ucell = (unsigned int)cell;          // ncells < 2^31
    unsigned int b = ucell / (unsigned int)spatial;
    unsigned int s = ucell - b * (unsigned int)spatial;

    if (cell + 3 < ncells && s + 3 < (unsigned int)spatial) {
        int4 iv = *reinterpret_cast<const int4*>(idxmap + cell);
        const bool vx = iv.x >= 0, vy = iv.y >= 0, vz = iv.z >= 0, vw = iv.w >= 0;
        const float* px = vf + (long long)iv.x * 64;
        const float* py = vf + (long long)iv.y * 64;
        const float* pz = vf + (long long)iv.z * 64;
        const float* pw = vf + (long long)iv.w * 64;
        float* op0 = out + ((long long)b * 64) * spatial + s;

        const float4 zero = make_float4(0.f, 0.f, 0.f, 0.f);
        #pragma unroll
        for (int p = 0; p < 4; ++p) {
            const int cbase = p * 16;
            float4 rx[4], ry[4], rz[4], rw[4];
            // ---- load phase: 16 float4 loads back-to-back ----
            #pragma unroll
            for (int k = 0; k < 4; ++k) {
                const int cc = cbase + k * 4;
                rx[k] = vx ? *reinterpret_cast<const float4*>(px + cc) : zero;
                ry[k] = vy ? *reinterpret_cast<const float4*>(py + cc) : zero;
                rz[k] = vz ? *reinterpret_cast<const float4*>(pz + cc) : zero;
                rw[k] = vw ? *reinterpret_cast<const float4*>(pw + cc) : zero;
            }
            // ---- store phase: 16 transposed float4 stores back-to-back ----
            #pragma unroll
            for (int k = 0; k < 4; ++k) {
                const int cc = cbase + k * 4;
                float* op = op0 + (long long)cc * spatial;
                *reinterpret_cast<float4*>(op) =
                    make_float4(rx[k].x, ry[k].x, rz[k].x, rw[k].x);
                op += spatial;
                *reinterpret_cast<float4*>(op) =
                    make_float4(rx[k].y, ry[k].y, rz[k].y, rw[k].y);
                op += spatial;
                *reinterpret_cast<float4*>(op) =
                    make_float4(rx[k].z, ry[k].z, rz[k].z, rw[k].z);
                op += spatial;
                *reinterpret_cast<float4*>(op) =
                    make_float4(rx[k].w, ry[k].w, rz[k].w, rw[k].w);
            }
        }
    } else {
        // tail / sample-boundary straddle: scalar per element
        for (int j = 0; j < 4; ++j) {
            long long cc = cell + j;
            if (cc >= ncells) break;
            long long bb = cc / spatial;
            long long ss = cc - bb * spatial;
            int idx = idxmap[cc];
            for (int c = 0; c < 64; ++c)
                out[(bb * 64 + c) * (long long)spatial + ss] =
                    (idx >= 0) ? vf[(long long)idx * 64 + c] : 0.0f;
        }
    }
}

// -------- generic gather (round-10 v5) for C != 64 ------------------------
__global__ __launch_bounds__(256)
void pps_gather_v5(const float* __restrict__ vf,
                   const int* __restrict__ idxmap,
                   const int* __restrict__ nz_p,
                   const int* __restrict__ ny_p,
                   const int* __restrict__ nx_p,
                   float* __restrict__ out,
                   int C, long long ncells) {
    const int spatial =
        __builtin_amdgcn_readfirstlane(nz_p[0] * ny_p[0] * nx_p[0]);
    const long long nquads = (ncells + 3) >> 2;
    long long q = blockIdx.x * (long long)blockDim.x + threadIdx.x;
    if (q >= nquads) return;
    long long cell = q << 2;
    unsigned int ucell = (unsigned int)cell;
    unsigned int b = ucell / (unsigned int)spatial;
    unsigned int s = ucell - b * (unsigned int)spatial;

    if (cell + 3 < ncells && s + 3 < (unsigned int)spatial && (C & 3) == 0) {
        int4 iv = *reinterpret_cast<const int4*>(idxmap + cell);
        const bool vx = iv.x >= 0, vy = iv.y >= 0, vz = iv.z >= 0, vw = iv.w >= 0;
        const float* px = vf + (long long)iv.x * C;
        const float* py = vf + (long long)iv.y * C;
        const float* pz = vf + (long long)iv.z * C;
        const float* pw = vf + (long long)iv.w * C;
        float* op0 = out + ((long long)b * C) * spatial + s;
        #pragma unroll 4
        for (int cc = 0; cc < C; cc += 4) {
            float4 rx = make_float4(0.f, 0.f, 0.f, 0.f);
            float4 ry = rx, rz = rx, rw = rx;
            if (vx) rx = *reinterpret_cast<const float4*>(px + cc);
            if (vy) ry = *reinterpret_cast<const float4*>(py + cc);
            if (vz) rz = *reinterpret_cast<const float4*>(pz + cc);
            if (vw) rw = *reinterpret_cast<const float4*>(pw + cc);
            float* op = op0 + (long long)cc * spatial;
            *reinterpret_cast<float4*>(op) = make_float4(rx.x, ry.x, rz.x, rw.x);
            op += spatial;
            *reinterpret_cast<float4*>(op) = make_float4(rx.y, ry.y, rz.y, rw.y);
            op += spatial;
            *reinterpret_cast<float4*>(op) = make_float4(rx.z, ry.z, rz.z, rw.z);
            op += spatial;
            *reinterpret_cast<float4*>(op) = make_float4(rx.w, ry.w, rz.w, rw.w);
        }
    } else {
        for (int j = 0; j < 4; ++j) {
            long long cc = cell + j;
            if (cc >= ncells) break;
            long long bb = cc / spatial;
            long long ss = cc - bb * spatial;
            int idx = idxmap[cc];
            for (int c = 0; c < C; ++c)
                out[(bb * C + c) * (long long)spatial + ss] =
                    (idx >= 0) ? vf[(long long)idx * C + c] : 0.0f;
        }
    }
}

// -------- fallback path (round-1): memset + direct scatter ----------------
__global__ void pps_scatter_kernel(const float* __restrict__ vf,
                                   const int* __restrict__ coords,
                                   const int* __restrict__ nz_p,
                                   const int* __restrict__ ny_p,
                                   const int* __restrict__ nx_p,
                                   float* __restrict__ out,
                                   int n_points, int C) {
    int idx = blockIdx.x * blockDim.x + threadIdx.x;
    int total = n_points * C;
    if (idx >= total) return;
    int n = idx / C;
    int c = idx - n * C;
    int nz = nz_p[0], ny = ny_p[0], nx = nx_p[0];
    long long spatial = (long long)nz * ny * nx;
    int b = coords[4 * n + 0];
    int z = coords[4 * n + 1];
    int y = coords[4 * n + 2];
    int x = coords[4 * n + 3];
    long long s = (long long)z * nz + (long long)y * nx + (long long)x;
    out[((long long)b * C + c) * spatial + s] = vf[idx];
}

extern "C" void kernel_launch(void* const* d_in, const int* in_sizes, int n_in,
                              void* d_out, int out_size, void* d_ws, size_t ws_size,
                              hipStream_t stream) {
    const float* vf     = (const float*)d_in[0];
    const int*   coords = (const int*)d_in[1];
    const int*   nz_p   = (const int*)d_in[3];
    const int*   ny_p   = (const int*)d_in[4];
    const int*   nx_p   = (const int*)d_in[5];
    float* out = (float*)d_out;

    int n_points = in_sizes[1] / 4;          // coords = [N,4]
    int C        = in_sizes[0] / n_points;   // vf = [N,C]
    long long ncells = (long long)out_size / C;   // B * spatial
    size_t idx_bytes = (size_t)ncells * sizeof(int);

    if (ws_size >= idx_bytes && ncells < 0x7FFFFFFFLL) {
        int* idxmap = (int*)d_ws;
        (void)hipMemsetAsync(idxmap, 0xFF, idx_bytes, stream);
        {
            int block = 256;
            int grid = (n_points + block - 1) / block;
            pps_build_idx<<<grid, block, 0, stream>>>(coords, nz_p, ny_p, nx_p,
                                                      idxmap, n_points);
        }
        long long nquads = (ncells + 3) / 4;
        long long gx = (nquads + 255) / 256;
        if (gx > 0x7FFFFFFF) gx = 0x7FFFFFFF;
        if (C == 64) {
            pps_gather_v7<<<(int)gx, 256, 0, stream>>>(vf, idxmap, nz_p, ny_p,
                                                       nx_p, out, ncells);
        } else {
            pps_gather_v5<<<(int)gx, 256, 0, stream>>>(vf, idxmap, nz_p, ny_p,
                                                       nx_p, out, C, ncells);
        }
    } else {
        (void)hipMemsetAsync(d_out, 0, (size_t)out_size * sizeof(float), stream);
        int total = n_points * C;
        int block = 256;
        int grid  = (total + block - 1) / block;
        pps_scatter_kernel<<<grid, block, 0, stream>>>(vf, coords, nz_p, ny_p,
                                                       nx_p, out, n_points, C);
    }
}